// Round 7
// baseline (473.344 us; speedup 1.0000x reference)
//
#include <hip/hip_runtime.h>
#include <cstdint>
#include <cstddef>

#define NN 50000
#define NE 800000
// DN=128, DE=64, H=8, C=16

typedef short bf16x8 __attribute__((ext_vector_type(8)));
typedef float f32x4 __attribute__((ext_vector_type(4)));

__device__ __forceinline__ float b2f(unsigned short s) {
  union { unsigned int u; float f; } x; x.u = ((unsigned int)s) << 16; return x.f;
}
__device__ __forceinline__ unsigned short f2b(float f) {
  union { float f; unsigned int u; } x; x.f = f;
  unsigned int r = x.u + 0x7FFFu + ((x.u >> 16) & 1u);
  return (unsigned short)(r >> 16);
}

// ---------------- ws layout (bytes) ----------------
#define WS_WCE    0u          // bf16 [64][128] (16KB)
#define WS_BCE    16384u      // f32 [128]
#define WS_WCEF   20480u      // bf16 frags (16KB)
#define WS_WALLF  40960u      // bf16 frags (128KB)
#define WS_BALL   172032u     // f32 [512]
#define WS_QB     180224u     // bf16 [NN][128]
#define WS_KB     12980224u   // bf16 [NN][128]
#define WS_VB     25780224u   // bf16 [NN][128]
#define WS_XR     38580224u   // f32  [NN][128]
#define WS_ATT    64180224u   // f32  [NN][128] (atomic accum)
#define WS_DEN    89780224u   // f32  [NN][8]   (atomic accum)
#define WS_CNT    91380224u   // int [NN]
#define WS_OFF    91580224u   // int [NN]
#define WS_CUR    91780224u   // int [NN]
#define WS_BSUM   91980224u   // int [256]
#define WS_EIDS   91984320u   // int [NE] (CSR slot -> orig edge)
#define WS_SRCS   95184320u   // int [NE] (CSR slot -> src node)
#define WS_DSTS   98384320u   // int [NE] (CSR slot -> dst node)
// end = 101,584,320 B

// W_ce = W_edge @ We (64x128, bf16), b_ce = b_edge @ We (f32)
__global__ void k_prep(const float* __restrict__ W_edge, const float* __restrict__ b_edge,
                       const float* __restrict__ We, unsigned short* __restrict__ wce,
                       float* __restrict__ bce) {
  int i = blockIdx.x;       // 0..63
  int j = threadIdx.x;      // 0..127
  float s = 0.f;
  for (int m = 0; m < 64; ++m) s += W_edge[i*64+m] * We[m*128+j];
  wce[i*128+j] = f2b(s);
  if (i == 0) {
    float bb = 0.f;
    for (int m = 0; m < 64; ++m) bb += b_edge[m] * We[m*128+j];
    bce[j] = bb;
  }
}

// pack wce [64][128] into A-frag layout
__global__ void k_pack_wce(const unsigned short* __restrict__ wce, unsigned short* __restrict__ wcef) {
  int fb = blockIdx.x;           // 0..15
  int ct = fb >> 1, s = fb & 1;
  int l = threadIdx.x;           // 0..63
  unsigned short* dst = wcef + (((size_t)(ct*2+s))*64 + l)*8;
  int col = ct*16 + (l & 15);
  int k0 = s*32 + (l >> 4)*8;
  #pragma unroll
  for (int j = 0; j < 8; ++j) dst[j] = wce[(k0+j)*128 + col];
}

// pack Wq/Wk/Wv/Wskip (fp32 [128][128], y=x@W layout) into bf16 A-frags
__global__ void k_pack_wall(const float* __restrict__ Wq, const float* __restrict__ Wk,
                            const float* __restrict__ Wv, const float* __restrict__ Ws,
                            unsigned short* __restrict__ wallf) {
  int fb = blockIdx.x;           // 0..127
  int mat = fb >> 5, ct = (fb >> 2) & 7, s = fb & 3;
  int l = threadIdx.x;
  const float* W = (mat==0) ? Wq : (mat==1) ? Wk : (mat==2) ? Wv : Ws;
  unsigned short* dst = wallf + ((((size_t)(mat*8+ct))*4 + s)*64 + l)*8;
  int col = ct*16 + (l & 15);
  int k0 = s*32 + (l >> 4)*8;
  #pragma unroll
  for (int j = 0; j < 8; ++j) dst[j] = f2b(W[(k0+j)*128 + col]);
}

__global__ void k_pack_bias(const float* __restrict__ bq, const float* __restrict__ bk,
                            const float* __restrict__ bv, const float* __restrict__ bs,
                            float* __restrict__ ball) {
  int m = blockIdx.x, c = threadIdx.x;
  const float* b = (m==0) ? bq : (m==1) ? bk : (m==2) ? bv : bs;
  ball[m*128 + c] = b[c];
}

// node linears via MFMA: grid = n_tiles*4, block 256 (4 waves)
__global__ void __launch_bounds__(256) k_node_mfma(const float* __restrict__ x,
    const unsigned short* __restrict__ wallf, const float* __restrict__ ball,
    unsigned short* __restrict__ qb, unsigned short* __restrict__ kb,
    unsigned short* __restrict__ vb, float* __restrict__ xr) {
  __shared__ unsigned short sA[128*128];   // 32KB, chunk-swizzled bf16
  int mat = blockIdx.x & 3;
  int n0 = (blockIdx.x >> 2) * 128;
  for (int i = 0; i < 8; ++i) {
    int c = threadIdx.x + i*256;       // 0..2047
    int row = c >> 4, ch = c & 15;
    int sw = (ch & 8) | ((ch & 7) ^ (row & 7));
    unsigned short tmp[8];
    if (n0 + row < NN) {
      const float* src = x + (size_t)(n0+row)*128 + ch*8;
      float4 f0 = *(const float4*)src;
      float4 f1 = *(const float4*)(src + 4);
      tmp[0]=f2b(f0.x); tmp[1]=f2b(f0.y); tmp[2]=f2b(f0.z); tmp[3]=f2b(f0.w);
      tmp[4]=f2b(f1.x); tmp[5]=f2b(f1.y); tmp[6]=f2b(f1.z); tmp[7]=f2b(f1.w);
    } else {
      #pragma unroll
      for (int j = 0; j < 8; ++j) tmp[j] = 0;
    }
    *(uint4*)&sA[row*128 + sw*8] = *(const uint4*)tmp;
  }
  __syncthreads();
  int l = threadIdx.x & 63, w = threadIdx.x >> 6;
  int g = l >> 4, ln = l & 15;
  f32x4 acc[2][8];
  #pragma unroll
  for (int rt = 0; rt < 2; ++rt)
    #pragma unroll
    for (int ct = 0; ct < 8; ++ct) acc[rt][ct] = (f32x4){0.f,0.f,0.f,0.f};
  for (int s = 0; s < 4; ++s) {
    bf16x8 wf[8];
    #pragma unroll
    for (int ct = 0; ct < 8; ++ct)
      wf[ct] = *(const bf16x8*)(wallf + ((((size_t)(mat*8+ct))*4 + s)*64 + l)*8);
    bf16x8 bfr[2];
    #pragma unroll
    for (int rt = 0; rt < 2; ++rt) {
      int row = w*32 + rt*16 + ln;
      int ch = s*4 + g;
      int sw = (ch & 8) | ((ch & 7) ^ (row & 7));
      bfr[rt] = *(const bf16x8*)&sA[row*128 + sw*8];
    }
    #pragma unroll
    for (int rt = 0; rt < 2; ++rt)
      #pragma unroll
      for (int ct = 0; ct < 8; ++ct)
        acc[rt][ct] = __builtin_amdgcn_mfma_f32_16x16x32_bf16(wf[ct], bfr[rt], acc[rt][ct], 0, 0, 0);
  }
  #pragma unroll
  for (int rt = 0; rt < 2; ++rt) {
    int node = n0 + w*32 + rt*16 + ln;
    if (node >= NN) continue;
    #pragma unroll
    for (int ct = 0; ct < 8; ++ct) {
      int c0 = ct*16 + g*4;
      float4 bi = *(const float4*)(ball + mat*128 + c0);
      float v0 = acc[rt][ct][0] + bi.x, v1 = acc[rt][ct][1] + bi.y;
      float v2 = acc[rt][ct][2] + bi.z, v3 = acc[rt][ct][3] + bi.w;
      if (mat == 3) {
        float4 o = {v0, v1, v2, v3};
        *(float4*)(xr + (size_t)node*128 + c0) = o;
      } else {
        unsigned short* dst = (mat==0) ? qb : (mat==1) ? kb : vb;
        unsigned short o[4] = {f2b(v0), f2b(v1), f2b(v2), f2b(v3)};
        *(uint2*)(dst + (size_t)node*128 + c0) = *(const uint2*)o;
      }
    }
  }
}

// -------- fully fused edge kernel --------
// Block owns 128 CSR-consecutive slots (dst-sorted). Gathers es rows by eids,
// MFMA -> e staged in LDS, then per-row cooperative epilogue: coalesced q/k/v
// row loads, 3-shuffle head dot, exp, and segmented register accumulation
// flushed to att/den via uncontended f32 atomics on dst change.
__global__ void __launch_bounds__(256) k_edge_fused(const float* __restrict__ es,
    const unsigned short* __restrict__ wcef, const float* __restrict__ bce,
    const int* __restrict__ eids, const int* __restrict__ srcs,
    const int* __restrict__ dsts,
    const unsigned short* __restrict__ qb, const unsigned short* __restrict__ kb,
    const unsigned short* __restrict__ vb,
    float* __restrict__ att, float* __restrict__ den) {
  __shared__ unsigned short sA[128*64];    // 16KB input staging (chunk-swizzled)
  __shared__ unsigned short sO[128*128];   // 32KB e staging (chunk-swizzled)
  __shared__ int sS[128], sD[128], sE[128];
  int e0 = blockIdx.x * 128;
  if (threadIdx.x < 128) {
    sE[threadIdx.x] = eids[e0 + threadIdx.x];
    sS[threadIdx.x] = srcs[e0 + threadIdx.x];
    sD[threadIdx.x] = dsts[e0 + threadIdx.x];
  }
  __syncthreads();
  for (int i = 0; i < 4; ++i) {
    int c = threadIdx.x + i*256;       // 0..1023
    int row = c >> 3, ch = c & 7;
    int sw = ch ^ (row & 7);
    const float* src = es + (size_t)sE[row]*64 + ch*8;
    float4 f0 = *(const float4*)src;
    float4 f1 = *(const float4*)(src + 4);
    unsigned short tmp[8];
    tmp[0]=f2b(f0.x); tmp[1]=f2b(f0.y); tmp[2]=f2b(f0.z); tmp[3]=f2b(f0.w);
    tmp[4]=f2b(f1.x); tmp[5]=f2b(f1.y); tmp[6]=f2b(f1.z); tmp[7]=f2b(f1.w);
    *(uint4*)&sA[row*64 + sw*8] = *(const uint4*)tmp;
  }
  __syncthreads();
  int l = threadIdx.x & 63, w = threadIdx.x >> 6;
  int g = l >> 4, ln = l & 15;
  f32x4 acc[2][8];
  #pragma unroll
  for (int rt = 0; rt < 2; ++rt)
    #pragma unroll
    for (int ct = 0; ct < 8; ++ct) acc[rt][ct] = (f32x4){0.f,0.f,0.f,0.f};
  #pragma unroll
  for (int s = 0; s < 2; ++s) {
    bf16x8 wf[8];
    #pragma unroll
    for (int ct = 0; ct < 8; ++ct)
      wf[ct] = *(const bf16x8*)(wcef + (((size_t)(ct*2+s))*64 + l)*8);
    bf16x8 bfr[2];
    #pragma unroll
    for (int rt = 0; rt < 2; ++rt) {
      int row = w*32 + rt*16 + ln;
      int ch = (s*4 + g) ^ (row & 7);
      bfr[rt] = *(const bf16x8*)&sA[row*64 + ch*8];
    }
    #pragma unroll
    for (int rt = 0; rt < 2; ++rt)
      #pragma unroll
      for (int ct = 0; ct < 8; ++ct)
        acc[rt][ct] = __builtin_amdgcn_mfma_f32_16x16x32_bf16(wf[ct], bfr[rt], acc[rt][ct], 0, 0, 0);
  }
  // stage e (+bias) bf16 into swizzled sO: channel c -> chunk c>>3, short c&7
  #pragma unroll
  for (int rt = 0; rt < 2; ++rt) {
    int row = w*32 + rt*16 + ln;
    #pragma unroll
    for (int ct = 0; ct < 8; ++ct) {
      int c0 = ct*16 + g*4;
      float4 bi = *(const float4*)(bce + c0);
      unsigned short o[4] = {f2b(acc[rt][ct][0]+bi.x), f2b(acc[rt][ct][1]+bi.y),
                             f2b(acc[rt][ct][2]+bi.z), f2b(acc[rt][ct][3]+bi.w)};
      int ch = ct*2 + (g >> 1);
      int sw = (ch & 8) | ((ch & 7) ^ (row & 7));
      *(uint2*)&sO[row*128 + sw*8 + (g & 1)*4] = *(const uint2*)o;
    }
  }
  __syncthreads();
  // per-row cooperative epilogue; lane l owns channels 2l,2l+1; head = l>>3
  int base = w*32;
  float a0 = 0.f, a1 = 0.f, dsum = 0.f;
  int curd = sD[base];
  for (int r = 0; r < 32; ++r) {
    int rr = base + r;
    int srcn = sS[rr], dstn = sD[rr];
    if (dstn != curd) {
      unsafeAtomicAdd(&att[(size_t)curd*128 + 2*l],     a0);
      unsafeAtomicAdd(&att[(size_t)curd*128 + 2*l + 1], a1);
      if ((l & 7) == 0) unsafeAtomicAdd(&den[(size_t)curd*8 + (l >> 3)], dsum);
      a0 = a1 = dsum = 0.f;
      curd = dstn;
    }
    unsigned int qv = *(const unsigned int*)(qb + (size_t)dstn*128 + 2*l);
    unsigned int kv = *(const unsigned int*)(kb + (size_t)srcn*128 + 2*l);
    unsigned int vv = *(const unsigned int*)(vb + (size_t)srcn*128 + 2*l);
    int ch = l >> 2;
    int sw = (ch & 8) | ((ch & 7) ^ (rr & 7));
    unsigned int ev = *(const unsigned int*)&sO[rr*128 + sw*8 + (l & 3)*2];
    float e0f = b2f((unsigned short)(ev & 0xffffu));
    float e1f = b2f((unsigned short)(ev >> 16));
    float p = b2f((unsigned short)(qv & 0xffffu)) * (b2f((unsigned short)(kv & 0xffffu)) + e0f)
            + b2f((unsigned short)(qv >> 16))     * (b2f((unsigned short)(kv >> 16))     + e1f);
    p += __shfl_xor(p, 1);
    p += __shfl_xor(p, 2);
    p += __shfl_xor(p, 4);
    float exv = __expf(p * 0.25f);
    a0 += exv * (b2f((unsigned short)(vv & 0xffffu)) + e0f);
    a1 += exv * (b2f((unsigned short)(vv >> 16))     + e1f);
    dsum += exv;
  }
  unsafeAtomicAdd(&att[(size_t)curd*128 + 2*l],     a0);
  unsafeAtomicAdd(&att[(size_t)curd*128 + 2*l + 1], a1);
  if ((l & 7) == 0) unsafeAtomicAdd(&den[(size_t)curd*8 + (l >> 3)], dsum);
}

// -------- CSR build --------
__global__ void __launch_bounds__(256) k_hist(const int* __restrict__ ei, int* __restrict__ cnt) {
  int t = blockIdx.x * 256 + threadIdx.x;
  if (t < NE) atomicAdd(&cnt[ei[NE + t]], 1);
}

__global__ void __launch_bounds__(256) k_scanA(const int* __restrict__ cnt,
    int* __restrict__ off, int* __restrict__ bsum) {
  __shared__ int s[256];
  int i = blockIdx.x * 256 + threadIdx.x;
  int v = (i < NN) ? cnt[i] : 0;
  s[threadIdx.x] = v;
  __syncthreads();
  #pragma unroll
  for (int d = 1; d < 256; d <<= 1) {
    int t = (threadIdx.x >= d) ? s[threadIdx.x - d] : 0;
    __syncthreads();
    s[threadIdx.x] += t;
    __syncthreads();
  }
  if (i < NN) off[i] = s[threadIdx.x] - v;
  if (threadIdx.x == 255) bsum[blockIdx.x] = s[255];
}

__global__ void __launch_bounds__(256) k_scanB(int* __restrict__ bsum, int nb) {
  __shared__ int s[256];
  int v = (threadIdx.x < nb) ? bsum[threadIdx.x] : 0;
  s[threadIdx.x] = v;
  __syncthreads();
  #pragma unroll
  for (int d = 1; d < 256; d <<= 1) {
    int t = (threadIdx.x >= d) ? s[threadIdx.x - d] : 0;
    __syncthreads();
    s[threadIdx.x] += t;
    __syncthreads();
  }
  if (threadIdx.x < nb) bsum[threadIdx.x] = s[threadIdx.x] - v;
}

__global__ void __launch_bounds__(256) k_scanC(int* __restrict__ off,
    const int* __restrict__ bsum, int* __restrict__ cur) {
  int i = blockIdx.x * 256 + threadIdx.x;
  if (i < NN) {
    int o = off[i] + bsum[blockIdx.x];
    off[i] = o;
    cur[i] = o;
  }
}

// records CSR slot -> orig edge / src node / dst node
__global__ void __launch_bounds__(256) k_scatter(const int* __restrict__ ei,
    int* __restrict__ cur, int* __restrict__ eids, int* __restrict__ srcs,
    int* __restrict__ dsts) {
  int t = blockIdx.x * 256 + threadIdx.x;
  if (t < NE) {
    int d = ei[NE + t];
    int p = atomicAdd(&cur[d], 1);
    eids[p] = t;
    srcs[p] = ei[t];
    dsts[p] = d;
  }
}

// -------- node epilogue: divide by den, beta-gate, LN, residual ReLU --------
__global__ void __launch_bounds__(256) k_final(
    const float* __restrict__ att, const float* __restrict__ den,
    const float* __restrict__ xr, const float* __restrict__ x,
    const float* __restrict__ Wb, const float* __restrict__ ln_g,
    const float* __restrict__ ln_b, float* __restrict__ out) {
  int wid = threadIdx.x >> 6, lane = threadIdx.x & 63;
  int n = blockIdx.x * 4 + wid;
  if (n >= NN) return;
  int c = lane * 2;

  float dh = den[(size_t)n*8 + (lane >> 3)];
  float inv = (dh > 0.f) ? 1.f / dh : 0.f;
  float2 o = *(const float2*)(att + (size_t)n*128 + c);
  float o0 = o.x * inv, o1 = o.y * inv;

  float2 r = *(const float2*)(xr + (size_t)n*128 + c);
  float p = o0*Wb[c] + o1*Wb[c+1] + r.x*Wb[128+c] + r.y*Wb[128+c+1]
          + (o0-r.x)*Wb[256+c] + (o1-r.y)*Wb[256+c+1];
  #pragma unroll
  for (int offs = 32; offs > 0; offs >>= 1) p += __shfl_xor(p, offs);
  float beta = 1.f / (1.f + __expf(-p));
  float g0 = beta*r.x + (1.f-beta)*o0;
  float g1 = beta*r.y + (1.f-beta)*o1;
  float msum = g0 + g1;
  #pragma unroll
  for (int offs = 32; offs > 0; offs >>= 1) msum += __shfl_xor(msum, offs);
  msum *= (1.f/128.f);
  float d0 = g0 - msum, d1 = g1 - msum;
  float vv = d0*d0 + d1*d1;
  #pragma unroll
  for (int offs = 32; offs > 0; offs >>= 1) vv += __shfl_xor(vv, offs);
  vv *= (1.f/128.f);
  float rs = rsqrtf(vv + 1e-5f);
  float n0 = d0*rs*ln_g[c]   + ln_b[c];
  float n1 = d1*rs*ln_g[c+1] + ln_b[c+1];
  float2 xv = *(const float2*)(x + (size_t)n*128 + c);
  float2 res;
  res.x = xv.x + fmaxf(n0, 0.f);
  res.y = xv.y + fmaxf(n1, 0.f);
  *(float2*)(out + (size_t)n*128 + c) = res;
}

extern "C" void kernel_launch(void* const* d_in, const int* in_sizes, int n_in,
                              void* d_out, int out_size, void* d_ws, size_t ws_size,
                              hipStream_t stream) {
  const float* node   = (const float*)d_in[0];
  const int*   ei     = (const int*)  d_in[1];
  const float* es     = (const float*)d_in[2];
  const float* W_edge = (const float*)d_in[3];
  const float* b_edge = (const float*)d_in[4];
  const float* Wq     = (const float*)d_in[5];
  const float* bq     = (const float*)d_in[6];
  const float* Wk     = (const float*)d_in[7];
  const float* bk     = (const float*)d_in[8];
  const float* Wv     = (const float*)d_in[9];
  const float* bv     = (const float*)d_in[10];
  const float* We     = (const float*)d_in[11];
  const float* Wskip  = (const float*)d_in[12];
  const float* bskip  = (const float*)d_in[13];
  const float* Wbeta  = (const float*)d_in[14];
  const float* ln_g   = (const float*)d_in[15];
  const float* ln_b   = (const float*)d_in[16];

  char* ws = (char*)d_ws;
  unsigned short* wce   = (unsigned short*)(ws + WS_WCE);
  float*          bce   = (float*)(ws + WS_BCE);
  unsigned short* wcef  = (unsigned short*)(ws + WS_WCEF);
  unsigned short* wallf = (unsigned short*)(ws + WS_WALLF);
  float*          ball  = (float*)(ws + WS_BALL);
  unsigned short* qb  = (unsigned short*)(ws + WS_QB);
  unsigned short* kb  = (unsigned short*)(ws + WS_KB);
  unsigned short* vb  = (unsigned short*)(ws + WS_VB);
  float*          xr  = (float*)(ws + WS_XR);
  float*          att = (float*)(ws + WS_ATT);
  float*          den = (float*)(ws + WS_DEN);
  int*            cnt = (int*)(ws + WS_CNT);
  int*            off = (int*)(ws + WS_OFF);
  int*            cur = (int*)(ws + WS_CUR);
  int*            bsm = (int*)(ws + WS_BSUM);
  int*            eids= (int*)(ws + WS_EIDS);
  int*            srcs= (int*)(ws + WS_SRCS);
  int*            dsts= (int*)(ws + WS_DSTS);

  hipMemsetAsync(cnt, 0, (size_t)NN*4, stream);
  hipMemsetAsync(att, 0, (size_t)NN*128*4, stream);
  hipMemsetAsync(den, 0, (size_t)NN*8*4, stream);

  k_prep<<<64, 128, 0, stream>>>(W_edge, b_edge, We, wce, bce);
  k_pack_wce<<<16, 64, 0, stream>>>(wce, wcef);
  k_pack_wall<<<128, 64, 0, stream>>>(Wq, Wk, Wv, Wskip, wallf);
  k_pack_bias<<<4, 128, 0, stream>>>(bq, bk, bv, bskip, ball);

  const int nbScan = (NN + 255)/256;  // 196
  k_hist<<<(NE + 255)/256, 256, 0, stream>>>(ei, cnt);
  k_scanA<<<nbScan, 256, 0, stream>>>(cnt, off, bsm);
  k_scanB<<<1, 256, 0, stream>>>(bsm, nbScan);
  k_scanC<<<nbScan, 256, 0, stream>>>(off, bsm, cur);
  k_scatter<<<(NE + 255)/256, 256, 0, stream>>>(ei, cur, eids, srcs, dsts);

  const int ntiles = (NN + 127) / 128;  // 391
  k_node_mfma<<<ntiles*4, 256, 0, stream>>>(node, wallf, ball, qb, kb, vb, xr);
  k_edge_fused<<<NE/128, 256, 0, stream>>>(es, wcef, bce, eids, srcs, dsts,
                                           qb, kb, vb, att, den);

  k_final<<<(NN + 3)/4, 256, 0, stream>>>(att, den, xr, node,
                                          Wbeta, ln_g, ln_b, (float*)d_out);
}

// Round 8
// 333.444 us; speedup vs baseline: 1.4196x; 1.4196x over previous
//
#include <hip/hip_runtime.h>
#include <cstdint>
#include <cstddef>

#define NN 50000
#define NE 800000
// DN=128, DE=64, H=8, C=16

typedef short bf16x8 __attribute__((ext_vector_type(8)));
typedef float f32x4 __attribute__((ext_vector_type(4)));
typedef float f32x2 __attribute__((ext_vector_type(2)));

__device__ __forceinline__ float b2f(unsigned short s) {
  union { unsigned int u; float f; } x; x.u = ((unsigned int)s) << 16; return x.f;
}
__device__ __forceinline__ unsigned short f2b(float f) {
  union { float f; unsigned int u; } x; x.f = f;
  unsigned int r = x.u + 0x7FFFu + ((x.u >> 16) & 1u);
  return (unsigned short)(r >> 16);
}

// ---------------- ws layout (bytes) ----------------
#define WS_WCE    0u          // bf16 [64][128] (16KB)
#define WS_BCE    16384u      // f32 [128]
#define WS_WCEF   20480u      // bf16 frags 8ct*2s*64l*8j (16KB)
#define WS_WALLF  40960u      // bf16 frags 4m*8ct*4s*64l*8j (128KB)
#define WS_BALL   172032u     // f32 [512]
#define WS_QB     180224u     // bf16 [NN][128]
#define WS_KB     12980224u   // bf16 [NN][128]
#define WS_VB     25780224u   // bf16 [NN][128]
#define WS_XR     38580224u   // f32  [NN][128]
#define WS_EB     64180224u   // fp8  [NE][128] (CSR-sorted rows; region oversized)
#define WS_CNT    268980224u  // int [NN]
#define WS_OFF    269180224u  // int [NN]
#define WS_CUR    269380224u  // int [NN]
#define WS_BSUM   269580224u  // int [256]
#define WS_POS    269584320u  // int [NE]
#define WS_SRCS   272784320u  // int [NE]
// end = 275,984,320 B

// W_ce = W_edge @ We (64x128, bf16), b_ce = b_edge @ We (f32)
__global__ void k_prep(const float* __restrict__ W_edge, const float* __restrict__ b_edge,
                       const float* __restrict__ We, unsigned short* __restrict__ wce,
                       float* __restrict__ bce) {
  int i = blockIdx.x;       // 0..63
  int j = threadIdx.x;      // 0..127
  float s = 0.f;
  for (int m = 0; m < 64; ++m) s += W_edge[i*64+m] * We[m*128+j];
  wce[i*128+j] = f2b(s);
  if (i == 0) {
    float bb = 0.f;
    for (int m = 0; m < 64; ++m) bb += b_edge[m] * We[m*128+j];
    bce[j] = bb;
  }
}

// pack wce [64][128] into A-frag layout
__global__ void k_pack_wce(const unsigned short* __restrict__ wce, unsigned short* __restrict__ wcef) {
  int fb = blockIdx.x;           // 0..15
  int ct = fb >> 1, s = fb & 1;
  int l = threadIdx.x;           // 0..63
  unsigned short* dst = wcef + (((size_t)(ct*2+s))*64 + l)*8;
  int col = ct*16 + (l & 15);
  int k0 = s*32 + (l >> 4)*8;
  #pragma unroll
  for (int j = 0; j < 8; ++j) dst[j] = wce[(k0+j)*128 + col];
}

// pack Wq/Wk/Wv/Wskip (fp32 [128][128], y=x@W layout) into bf16 A-frags
__global__ void k_pack_wall(const float* __restrict__ Wq, const float* __restrict__ Wk,
                            const float* __restrict__ Wv, const float* __restrict__ Ws,
                            unsigned short* __restrict__ wallf) {
  int fb = blockIdx.x;           // 0..127
  int mat = fb >> 5, ct = (fb >> 2) & 7, s = fb & 3;
  int l = threadIdx.x;
  const float* W = (mat==0) ? Wq : (mat==1) ? Wk : (mat==2) ? Wv : Ws;
  unsigned short* dst = wallf + ((((size_t)(mat*8+ct))*4 + s)*64 + l)*8;
  int col = ct*16 + (l & 15);
  int k0 = s*32 + (l >> 4)*8;
  #pragma unroll
  for (int j = 0; j < 8; ++j) dst[j] = f2b(W[(k0+j)*128 + col]);
}

__global__ void k_pack_bias(const float* __restrict__ bq, const float* __restrict__ bk,
                            const float* __restrict__ bv, const float* __restrict__ bs,
                            float* __restrict__ ball) {
  int m = blockIdx.x, c = threadIdx.x;
  const float* b = (m==0) ? bq : (m==1) ? bk : (m==2) ? bv : bs;
  ball[m*128 + c] = b[c];
}

// node linears via MFMA: grid = n_tiles*4, block 256 (4 waves)
__global__ void __launch_bounds__(256) k_node_mfma(const float* __restrict__ x,
    const unsigned short* __restrict__ wallf, const float* __restrict__ ball,
    unsigned short* __restrict__ qb, unsigned short* __restrict__ kb,
    unsigned short* __restrict__ vb, float* __restrict__ xr) {
  __shared__ unsigned short sA[128*128];   // 32KB, chunk-swizzled bf16
  int mat = blockIdx.x & 3;
  int n0 = (blockIdx.x >> 2) * 128;
  for (int i = 0; i < 8; ++i) {
    int c = threadIdx.x + i*256;       // 0..2047
    int row = c >> 4, ch = c & 15;
    int sw = (ch & 8) | ((ch & 7) ^ (row & 7));
    unsigned short tmp[8];
    if (n0 + row < NN) {
      const float* src = x + (size_t)(n0+row)*128 + ch*8;
      float4 f0 = *(const float4*)src;
      float4 f1 = *(const float4*)(src + 4);
      tmp[0]=f2b(f0.x); tmp[1]=f2b(f0.y); tmp[2]=f2b(f0.z); tmp[3]=f2b(f0.w);
      tmp[4]=f2b(f1.x); tmp[5]=f2b(f1.y); tmp[6]=f2b(f1.z); tmp[7]=f2b(f1.w);
    } else {
      #pragma unroll
      for (int j = 0; j < 8; ++j) tmp[j] = 0;
    }
    *(uint4*)&sA[row*128 + sw*8] = *(const uint4*)tmp;
  }
  __syncthreads();
  int l = threadIdx.x & 63, w = threadIdx.x >> 6;
  int g = l >> 4, ln = l & 15;
  f32x4 acc[2][8];
  #pragma unroll
  for (int rt = 0; rt < 2; ++rt)
    #pragma unroll
    for (int ct = 0; ct < 8; ++ct) acc[rt][ct] = (f32x4){0.f,0.f,0.f,0.f};
  for (int s = 0; s < 4; ++s) {
    bf16x8 wf[8];
    #pragma unroll
    for (int ct = 0; ct < 8; ++ct)
      wf[ct] = *(const bf16x8*)(wallf + ((((size_t)(mat*8+ct))*4 + s)*64 + l)*8);
    bf16x8 bfr[2];
    #pragma unroll
    for (int rt = 0; rt < 2; ++rt) {
      int row = w*32 + rt*16 + ln;
      int ch = s*4 + g;
      int sw = (ch & 8) | ((ch & 7) ^ (row & 7));
      bfr[rt] = *(const bf16x8*)&sA[row*128 + sw*8];
    }
    #pragma unroll
    for (int rt = 0; rt < 2; ++rt)
      #pragma unroll
      for (int ct = 0; ct < 8; ++ct)
        acc[rt][ct] = __builtin_amdgcn_mfma_f32_16x16x32_bf16(wf[ct], bfr[rt], acc[rt][ct], 0, 0, 0);
  }
  #pragma unroll
  for (int rt = 0; rt < 2; ++rt) {
    int node = n0 + w*32 + rt*16 + ln;
    if (node >= NN) continue;
    #pragma unroll
    for (int ct = 0; ct < 8; ++ct) {
      int c0 = ct*16 + g*4;
      float4 bi = *(const float4*)(ball + mat*128 + c0);
      float v0 = acc[rt][ct][0] + bi.x, v1 = acc[rt][ct][1] + bi.y;
      float v2 = acc[rt][ct][2] + bi.z, v3 = acc[rt][ct][3] + bi.w;
      if (mat == 3) {
        float4 o = {v0, v1, v2, v3};
        *(float4*)(xr + (size_t)node*128 + c0) = o;
      } else {
        unsigned short* dst = (mat==0) ? qb : (mat==1) ? kb : vb;
        unsigned short o[4] = {f2b(v0), f2b(v1), f2b(v2), f2b(v3)};
        *(uint2*)(dst + (size_t)node*128 + c0) = *(const uint2*)o;
      }
    }
  }
}

// edge GEMM via MFMA; output rows in FP8-E4M3 (1B/ch), CSR-scattered via pos,
// staged through LDS so each global store covers full 128B rows (8 lanes x 16B)
__global__ void __launch_bounds__(256) k_egemm_mfma(const float* __restrict__ es,
    const unsigned short* __restrict__ wcef, const float* __restrict__ bce,
    const int* __restrict__ pos, unsigned char* __restrict__ eb) {
  __shared__ unsigned short sA[128*64];      // 16KB input staging (chunk-swizzled)
  __shared__ unsigned char  sO8[128*160];    // 20KB fp8 output staging (stride 160B)
  int e0 = blockIdx.x * 128;
  for (int i = 0; i < 4; ++i) {
    int c = threadIdx.x + i*256;       // 0..1023
    int row = c >> 3, ch = c & 7;
    int sw = ch ^ (row & 7);
    const float* src = es + (size_t)(e0+row)*64 + ch*8;
    float4 f0 = *(const float4*)src;
    float4 f1 = *(const float4*)(src + 4);
    unsigned short tmp[8];
    tmp[0]=f2b(f0.x); tmp[1]=f2b(f0.y); tmp[2]=f2b(f0.z); tmp[3]=f2b(f0.w);
    tmp[4]=f2b(f1.x); tmp[5]=f2b(f1.y); tmp[6]=f2b(f1.z); tmp[7]=f2b(f1.w);
    *(uint4*)&sA[row*64 + sw*8] = *(const uint4*)tmp;
  }
  __syncthreads();
  int l = threadIdx.x & 63, w = threadIdx.x >> 6;
  int g = l >> 4, ln = l & 15;
  f32x4 acc[2][8];
  #pragma unroll
  for (int rt = 0; rt < 2; ++rt)
    #pragma unroll
    for (int ct = 0; ct < 8; ++ct) acc[rt][ct] = (f32x4){0.f,0.f,0.f,0.f};
  #pragma unroll
  for (int s = 0; s < 2; ++s) {
    bf16x8 wf[8];
    #pragma unroll
    for (int ct = 0; ct < 8; ++ct)
      wf[ct] = *(const bf16x8*)(wcef + (((size_t)(ct*2+s))*64 + l)*8);
    bf16x8 bfr[2];
    #pragma unroll
    for (int rt = 0; rt < 2; ++rt) {
      int row = w*32 + rt*16 + ln;
      int ch = (s*4 + g) ^ (row & 7);
      bfr[rt] = *(const bf16x8*)&sA[row*64 + ch*8];
    }
    #pragma unroll
    for (int rt = 0; rt < 2; ++rt)
      #pragma unroll
      for (int ct = 0; ct < 8; ++ct)
        acc[rt][ct] = __builtin_amdgcn_mfma_f32_16x16x32_bf16(wf[ct], bfr[rt], acc[rt][ct], 0, 0, 0);
  }
  // stage D-frags (+bias) as packed fp8 into swizzled LDS
  #pragma unroll
  for (int rt = 0; rt < 2; ++rt) {
    int row = w*32 + rt*16 + ln;
    #pragma unroll
    for (int ct = 0; ct < 8; ++ct) {
      int c0 = ct*16 + g*4;
      float4 bi = *(const float4*)(bce + c0);
      int pk = 0;
      pk = __builtin_amdgcn_cvt_pk_fp8_f32(acc[rt][ct][0]+bi.x, acc[rt][ct][1]+bi.y, pk, false);
      pk = __builtin_amdgcn_cvt_pk_fp8_f32(acc[rt][ct][2]+bi.z, acc[rt][ct][3]+bi.w, pk, true);
      int ch = ct ^ (row & 7);                 // 16B chunk swizzle (8 chunks/row)
      *(int*)&sO8[row*160 + ch*16 + g*4] = pk;
    }
  }
  __syncthreads();
  // readback: 8 lanes x 16B = one full 128B row per 8-lane group
  int rrow = threadIdx.x >> 3;   // 0..31
  int rch  = threadIdx.x & 7;
  #pragma unroll
  for (int it = 0; it < 4; ++it) {
    int r = it*32 + rrow;
    int swc = rch ^ (r & 7);
    uint4 val = *(const uint4*)&sO8[r*160 + swc*16];
    int prow = pos[e0 + r];
    *(uint4*)(eb + (size_t)prow*128 + rch*16) = val;
  }
}

// -------- CSR build --------
__global__ void __launch_bounds__(256) k_hist(const int* __restrict__ ei, int* __restrict__ cnt) {
  int t = blockIdx.x * 256 + threadIdx.x;
  if (t < NE) atomicAdd(&cnt[ei[NE + t]], 1);
}

__global__ void __launch_bounds__(256) k_scanA(const int* __restrict__ cnt,
    int* __restrict__ off, int* __restrict__ bsum) {
  __shared__ int s[256];
  int i = blockIdx.x * 256 + threadIdx.x;
  int v = (i < NN) ? cnt[i] : 0;
  s[threadIdx.x] = v;
  __syncthreads();
  #pragma unroll
  for (int d = 1; d < 256; d <<= 1) {
    int t = (threadIdx.x >= d) ? s[threadIdx.x - d] : 0;
    __syncthreads();
    s[threadIdx.x] += t;
    __syncthreads();
  }
  if (i < NN) off[i] = s[threadIdx.x] - v;
  if (threadIdx.x == 255) bsum[blockIdx.x] = s[255];
}

__global__ void __launch_bounds__(256) k_scanB(int* __restrict__ bsum, int nb) {
  __shared__ int s[256];
  int v = (threadIdx.x < nb) ? bsum[threadIdx.x] : 0;
  s[threadIdx.x] = v;
  __syncthreads();
  #pragma unroll
  for (int d = 1; d < 256; d <<= 1) {
    int t = (threadIdx.x >= d) ? s[threadIdx.x - d] : 0;
    __syncthreads();
    s[threadIdx.x] += t;
    __syncthreads();
  }
  if (threadIdx.x < nb) bsum[threadIdx.x] = s[threadIdx.x] - v;
}

__global__ void __launch_bounds__(256) k_scanC(int* __restrict__ off,
    const int* __restrict__ bsum, int* __restrict__ cur) {
  int i = blockIdx.x * 256 + threadIdx.x;
  if (i < NN) {
    int o = off[i] + bsum[blockIdx.x];
    off[i] = o;
    cur[i] = o;
  }
}

// records each edge's CSR slot (pos) and the slot's source node (srcs)
__global__ void __launch_bounds__(256) k_scatter(const int* __restrict__ ei,
    int* __restrict__ cur, int* __restrict__ pos, int* __restrict__ srcs) {
  int t = blockIdx.x * 256 + threadIdx.x;
  if (t < NE) {
    int d = ei[NE + t];
    int p = atomicAdd(&cur[d], 1);
    pos[t] = p;
    srcs[p] = ei[t];
  }
}

// -------- fused attention gather + beta-gate + LN + residual ReLU --------
// one wave per node; lane l owns channels 2l, 2l+1; head = l>>3
// eb rows CSR-sorted fp8: node n's edges are rows off[n]..off[n]+cnt[n]-1
__global__ void __launch_bounds__(256) k_attn(
    const int* __restrict__ off, const int* __restrict__ cnt,
    const int* __restrict__ srcs,
    const unsigned short* __restrict__ qb, const unsigned short* __restrict__ kb,
    const unsigned short* __restrict__ vb, const unsigned char* __restrict__ eb,
    const float* __restrict__ xr, const float* __restrict__ x,
    const float* __restrict__ Wb, const float* __restrict__ ln_g,
    const float* __restrict__ ln_b, float* __restrict__ out) {
  int wid = threadIdx.x >> 6, lane = threadIdx.x & 63;
  int n = blockIdx.x * 4 + wid;
  if (n >= NN) return;
  int c = lane * 2;

  unsigned int qu = *(const unsigned int*)(qb + (size_t)n*128 + c);
  float q0 = b2f((unsigned short)(qu & 0xffffu)), q1 = b2f((unsigned short)(qu >> 16));

  int start = off[n], m = cnt[n];
  const int* sp = srcs + start;
  const unsigned char* ep = eb + (size_t)start*128 + c;   // 2 bytes (2 fp8) per lane
  float acc0 = 0.f, acc1 = 0.f, den = 0.f;

  auto body = [&](unsigned int ku, unsigned int eu16, unsigned int vu) {
    f32x2 ef = __builtin_amdgcn_cvt_pk_f32_fp8((int)eu16, false);
    float e0 = ef[0], e1 = ef[1];
    float p = q0*(b2f((unsigned short)(ku & 0xffffu)) + e0)
            + q1*(b2f((unsigned short)(ku >> 16)) + e1);
    p += __shfl_xor(p, 1);
    p += __shfl_xor(p, 2);
    p += __shfl_xor(p, 4);
    float a = __expf(p * 0.25f);
    den  += a;
    acc0 += a * (b2f((unsigned short)(vu & 0xffffu)) + e0);
    acc1 += a * (b2f((unsigned short)(vu >> 16)) + e1);
  };

  int i = 0;
  for (; i + 4 <= m; i += 4) {
    int sA = sp[i], sB = sp[i+1], sC = sp[i+2], sD = sp[i+3];
    unsigned int euA = *(const unsigned short*)(ep + (size_t)(i+0)*128);
    unsigned int euB = *(const unsigned short*)(ep + (size_t)(i+1)*128);
    unsigned int euC = *(const unsigned short*)(ep + (size_t)(i+2)*128);
    unsigned int euD = *(const unsigned short*)(ep + (size_t)(i+3)*128);
    unsigned int kuA = *(const unsigned int*)(kb + (size_t)sA*128 + c);
    unsigned int vuA = *(const unsigned int*)(vb + (size_t)sA*128 + c);
    unsigned int kuB = *(const unsigned int*)(kb + (size_t)sB*128 + c);
    unsigned int vuB = *(const unsigned int*)(vb + (size_t)sB*128 + c);
    unsigned int kuC = *(const unsigned int*)(kb + (size_t)sC*128 + c);
    unsigned int vuC = *(const unsigned int*)(vb + (size_t)sC*128 + c);
    unsigned int kuD = *(const unsigned int*)(kb + (size_t)sD*128 + c);
    unsigned int vuD = *(const unsigned int*)(vb + (size_t)sD*128 + c);
    body(kuA, euA, vuA);
    body(kuB, euB, vuB);
    body(kuC, euC, vuC);
    body(kuD, euD, vuD);
  }
  for (; i < m; ++i) {
    int sA = sp[i];
    unsigned int euA = *(const unsigned short*)(ep + (size_t)i*128);
    unsigned int kuA = *(const unsigned int*)(kb + (size_t)sA*128 + c);
    unsigned int vuA = *(const unsigned int*)(vb + (size_t)sA*128 + c);
    body(kuA, euA, vuA);
  }

  float inv = (m > 0) ? 1.f / den : 0.f;
  float o0 = acc0 * inv, o1 = acc1 * inv;

  // epilogue
  float2 r = *(const float2*)(xr + (size_t)n*128 + c);
  float p = o0*Wb[c] + o1*Wb[c+1] + r.x*Wb[128+c] + r.y*Wb[128+c+1]
          + (o0-r.x)*Wb[256+c] + (o1-r.y)*Wb[256+c+1];
  #pragma unroll
  for (int offs = 32; offs > 0; offs >>= 1) p += __shfl_xor(p, offs);
  float beta = 1.f / (1.f + __expf(-p));
  float g0 = beta*r.x + (1.f-beta)*o0;
  float g1 = beta*r.y + (1.f-beta)*o1;
  float msum = g0 + g1;
  #pragma unroll
  for (int offs = 32; offs > 0; offs >>= 1) msum += __shfl_xor(msum, offs);
  msum *= (1.f/128.f);
  float d0 = g0 - msum, d1 = g1 - msum;
  float vv = d0*d0 + d1*d1;
  #pragma unroll
  for (int offs = 32; offs > 0; offs >>= 1) vv += __shfl_xor(vv, offs);
  vv *= (1.f/128.f);
  float rs = rsqrtf(vv + 1e-5f);
  float n0 = d0*rs*ln_g[c]   + ln_b[c];
  float n1 = d1*rs*ln_g[c+1] + ln_b[c+1];
  float2 xv = *(const float2*)(x + (size_t)n*128 + c);
  float2 res;
  res.x = xv.x + fmaxf(n0, 0.f);
  res.y = xv.y + fmaxf(n1, 0.f);
  *(float2*)(out + (size_t)n*128 + c) = res;
}

extern "C" void kernel_launch(void* const* d_in, const int* in_sizes, int n_in,
                              void* d_out, int out_size, void* d_ws, size_t ws_size,
                              hipStream_t stream) {
  const float* node   = (const float*)d_in[0];
  const int*   ei     = (const int*)  d_in[1];
  const float* es     = (const float*)d_in[2];
  const float* W_edge = (const float*)d_in[3];
  const float* b_edge = (const float*)d_in[4];
  const float* Wq     = (const float*)d_in[5];
  const float* bq     = (const float*)d_in[6];
  const float* Wk     = (const float*)d_in[7];
  const float* bk     = (const float*)d_in[8];
  const float* Wv     = (const float*)d_in[9];
  const float* bv     = (const float*)d_in[10];
  const float* We     = (const float*)d_in[11];
  const float* Wskip  = (const float*)d_in[12];
  const float* bskip  = (const float*)d_in[13];
  const float* Wbeta  = (const float*)d_in[14];
  const float* ln_g   = (const float*)d_in[15];
  const float* ln_b   = (const float*)d_in[16];

  char* ws = (char*)d_ws;
  unsigned short* wce   = (unsigned short*)(ws + WS_WCE);
  float*          bce   = (float*)(ws + WS_BCE);
  unsigned short* wcef  = (unsigned short*)(ws + WS_WCEF);
  unsigned short* wallf = (unsigned short*)(ws + WS_WALLF);
  float*          ball  = (float*)(ws + WS_BALL);
  unsigned short* qb  = (unsigned short*)(ws + WS_QB);
  unsigned short* kb  = (unsigned short*)(ws + WS_KB);
  unsigned short* vb  = (unsigned short*)(ws + WS_VB);
  float*          xr  = (float*)(ws + WS_XR);
  unsigned char*  eb  = (unsigned char*)(ws + WS_EB);
  int*            cnt = (int*)(ws + WS_CNT);
  int*            off = (int*)(ws + WS_OFF);
  int*            cur = (int*)(ws + WS_CUR);
  int*            bsm = (int*)(ws + WS_BSUM);
  int*            pos = (int*)(ws + WS_POS);
  int*            srcs= (int*)(ws + WS_SRCS);

  hipMemsetAsync(cnt, 0, (size_t)NN*4, stream);

  k_prep<<<64, 128, 0, stream>>>(W_edge, b_edge, We, wce, bce);
  k_pack_wce<<<16, 64, 0, stream>>>(wce, wcef);
  k_pack_wall<<<128, 64, 0, stream>>>(Wq, Wk, Wv, Wskip, wallf);
  k_pack_bias<<<4, 128, 0, stream>>>(bq, bk, bv, bskip, ball);

  const int nbScan = (NN + 255)/256;  // 196
  k_hist<<<(NE + 255)/256, 256, 0, stream>>>(ei, cnt);
  k_scanA<<<nbScan, 256, 0, stream>>>(cnt, off, bsm);
  k_scanB<<<1, 256, 0, stream>>>(bsm, nbScan);
  k_scanC<<<nbScan, 256, 0, stream>>>(off, bsm, cur);
  k_scatter<<<(NE + 255)/256, 256, 0, stream>>>(ei, cur, pos, srcs);

  const int ntiles = (NN + 127) / 128;  // 391
  k_node_mfma<<<ntiles*4, 256, 0, stream>>>(node, wallf, ball, qb, kb, vb, xr);
  k_egemm_mfma<<<NE/128, 256, 0, stream>>>(es, wcef, bce, pos, eb);

  k_attn<<<(NN + 3)/4, 256, 0, stream>>>(off, cnt, srcs, qb, kb, vb, eb,
                                         xr, node, Wbeta, ln_g, ln_b, (float*)d_out);
}

// Round 9
// 284.386 us; speedup vs baseline: 1.6644x; 1.1725x over previous
//
#include <hip/hip_runtime.h>
#include <cstdint>
#include <cstddef>

#define NN 50000
#define NE 800000
// DN=128, DE=64, H=8, C=16

typedef short bf16x8 __attribute__((ext_vector_type(8)));
typedef float f32x4 __attribute__((ext_vector_type(4)));
typedef float f32x2 __attribute__((ext_vector_type(2)));

__device__ __forceinline__ float b2f(unsigned short s) {
  union { unsigned int u; float f; } x; x.u = ((unsigned int)s) << 16; return x.f;
}
__device__ __forceinline__ unsigned short f2b(float f) {
  union { float f; unsigned int u; } x; x.f = f;
  unsigned int r = x.u + 0x7FFFu + ((x.u >> 16) & 1u);
  return (unsigned short)(r >> 16);
}

// ---------------- ws layout (bytes) ----------------
#define WS_WCE    0u          // bf16 [64][128] (16KB)
#define WS_BCE    16384u      // f32 [128]
#define WS_WCEF   20480u      // bf16 frags 8ct*2s*64l*8j (16KB)
#define WS_WALLF  40960u      // bf16 frags 4m*8ct*4s*64l*8j (128KB)
#define WS_BALL   172032u     // f32 [512]
#define WS_QB     180224u     // bf16 [NN][128]
#define WS_KB     12980224u   // fp8 [NN][128] (region oversized)
#define WS_VB     25780224u   // fp8 [NN][128] (region oversized)
#define WS_XR     38580224u   // f32  [NN][128]
#define WS_EB     64180224u   // fp8  [NE][128] (CSR-sorted rows; region oversized)
#define WS_CNT    268980224u  // int [NN]
#define WS_OFF    269180224u  // int [NN]
#define WS_CUR    269380224u  // int [NN]
#define WS_BSUM   269580224u  // int [256]
#define WS_POS    269584320u  // int [NE]
#define WS_SRCS   272784320u  // int [NE]
// end = 275,984,320 B

// W_ce = W_edge @ We (64x128, bf16), b_ce = b_edge @ We (f32)
__global__ void k_prep(const float* __restrict__ W_edge, const float* __restrict__ b_edge,
                       const float* __restrict__ We, unsigned short* __restrict__ wce,
                       float* __restrict__ bce) {
  int i = blockIdx.x;       // 0..63
  int j = threadIdx.x;      // 0..127
  float s = 0.f;
  for (int m = 0; m < 64; ++m) s += W_edge[i*64+m] * We[m*128+j];
  wce[i*128+j] = f2b(s);
  if (i == 0) {
    float bb = 0.f;
    for (int m = 0; m < 64; ++m) bb += b_edge[m] * We[m*128+j];
    bce[j] = bb;
  }
}

// pack wce [64][128] into A-frag layout
__global__ void k_pack_wce(const unsigned short* __restrict__ wce, unsigned short* __restrict__ wcef) {
  int fb = blockIdx.x;           // 0..15
  int ct = fb >> 1, s = fb & 1;
  int l = threadIdx.x;           // 0..63
  unsigned short* dst = wcef + (((size_t)(ct*2+s))*64 + l)*8;
  int col = ct*16 + (l & 15);
  int k0 = s*32 + (l >> 4)*8;
  #pragma unroll
  for (int j = 0; j < 8; ++j) dst[j] = wce[(k0+j)*128 + col];
}

// pack Wq/Wk/Wv/Wskip (fp32 [128][128], y=x@W layout) into bf16 A-frags
__global__ void k_pack_wall(const float* __restrict__ Wq, const float* __restrict__ Wk,
                            const float* __restrict__ Wv, const float* __restrict__ Ws,
                            unsigned short* __restrict__ wallf) {
  int fb = blockIdx.x;           // 0..127
  int mat = fb >> 5, ct = (fb >> 2) & 7, s = fb & 3;
  int l = threadIdx.x;
  const float* W = (mat==0) ? Wq : (mat==1) ? Wk : (mat==2) ? Wv : Ws;
  unsigned short* dst = wallf + ((((size_t)(mat*8+ct))*4 + s)*64 + l)*8;
  int col = ct*16 + (l & 15);
  int k0 = s*32 + (l >> 4)*8;
  #pragma unroll
  for (int j = 0; j < 8; ++j) dst[j] = f2b(W[(k0+j)*128 + col]);
}

__global__ void k_pack_bias(const float* __restrict__ bq, const float* __restrict__ bk,
                            const float* __restrict__ bv, const float* __restrict__ bs,
                            float* __restrict__ ball) {
  int m = blockIdx.x, c = threadIdx.x;
  const float* b = (m==0) ? bq : (m==1) ? bk : (m==2) ? bv : bs;
  ball[m*128 + c] = b[c];
}

// ---------- fused MFMA kernel: node linears (1/5 of blocks) + edge GEMM (4/5) ----------
// node tiles: 64 nodes x 128 cols of one matrix (q bf16 / k,v fp8 / skip f32)
// edge tiles: 64 edges; output fp8 rows CSR-scattered via pos, LDS-staged stores
__global__ void __launch_bounds__(256) k_mfma_all(
    const float* __restrict__ x, const unsigned short* __restrict__ wallf,
    const float* __restrict__ ball,
    unsigned short* __restrict__ qb, unsigned char* __restrict__ kb,
    unsigned char* __restrict__ vb, float* __restrict__ xr,
    const float* __restrict__ es, const unsigned short* __restrict__ wcef,
    const float* __restrict__ bce, const int* __restrict__ pos,
    unsigned char* __restrict__ eb) {
  __shared__ char smem[18432];
  int b = blockIdx.x;
  int l = threadIdx.x & 63, w = threadIdx.x >> 6;
  int g = l >> 4, ln = l & 15;

  if (b % 5 == 0) {
    // ---- node linears tile ----
    int tile = b / 5;
    if (tile >= ((NN + 63)/64) * 4) return;
    int mat = tile & 3;
    int n0 = (tile >> 2) * 64;
    unsigned short* sA = (unsigned short*)smem;   // [64][128] bf16, swizzled
    for (int i = 0; i < 4; ++i) {
      int c = threadIdx.x + i*256;       // 0..1023
      int row = c >> 4, ch = c & 15;
      int sw = (ch & 8) | ((ch & 7) ^ (row & 7));
      unsigned short tmp[8];
      if (n0 + row < NN) {
        const float* src = x + (size_t)(n0+row)*128 + ch*8;
        float4 f0 = *(const float4*)src;
        float4 f1 = *(const float4*)(src + 4);
        tmp[0]=f2b(f0.x); tmp[1]=f2b(f0.y); tmp[2]=f2b(f0.z); tmp[3]=f2b(f0.w);
        tmp[4]=f2b(f1.x); tmp[5]=f2b(f1.y); tmp[6]=f2b(f1.z); tmp[7]=f2b(f1.w);
      } else {
        #pragma unroll
        for (int j = 0; j < 8; ++j) tmp[j] = 0;
      }
      *(uint4*)&sA[row*128 + sw*8] = *(const uint4*)tmp;
    }
    __syncthreads();
    f32x4 acc[8];
    #pragma unroll
    for (int ct = 0; ct < 8; ++ct) acc[ct] = (f32x4){0.f,0.f,0.f,0.f};
    int row = w*16 + ln;
    for (int s = 0; s < 4; ++s) {
      int ch = s*4 + g;
      int sw = (ch & 8) | ((ch & 7) ^ (row & 7));
      bf16x8 bfr = *(const bf16x8*)&sA[row*128 + sw*8];
      #pragma unroll
      for (int ct = 0; ct < 8; ++ct) {
        bf16x8 wf = *(const bf16x8*)(wallf + ((((size_t)(mat*8+ct))*4 + s)*64 + l)*8);
        acc[ct] = __builtin_amdgcn_mfma_f32_16x16x32_bf16(wf, bfr, acc[ct], 0, 0, 0);
      }
    }
    int node = n0 + row;
    if (node >= NN) return;
    #pragma unroll
    for (int ct = 0; ct < 8; ++ct) {
      int c0 = ct*16 + g*4;
      float4 bi = *(const float4*)(ball + mat*128 + c0);
      float v0 = acc[ct][0] + bi.x, v1 = acc[ct][1] + bi.y;
      float v2 = acc[ct][2] + bi.z, v3 = acc[ct][3] + bi.w;
      if (mat == 3) {
        float4 o = {v0, v1, v2, v3};
        *(float4*)(xr + (size_t)node*128 + c0) = o;
      } else if (mat == 0) {
        unsigned short o[4] = {f2b(v0), f2b(v1), f2b(v2), f2b(v3)};
        *(uint2*)(qb + (size_t)node*128 + c0) = *(const uint2*)o;
      } else {
        int pk = 0;
        pk = __builtin_amdgcn_cvt_pk_fp8_f32(v0, v1, pk, false);
        pk = __builtin_amdgcn_cvt_pk_fp8_f32(v2, v3, pk, true);
        unsigned char* dst = (mat==1) ? kb : vb;
        *(int*)(dst + (size_t)node*128 + c0) = pk;
      }
    }
  } else {
    // ---- edge GEMM tile (64 edges) ----
    int tile = b - b/5 - 1;
    if (tile >= NE/64) return;
    int e0 = tile * 64;
    unsigned short* sA = (unsigned short*)smem;            // [64][64] bf16 (8KB)
    unsigned char*  sO8 = (unsigned char*)(smem + 8192);   // [64][160] fp8 (10KB)
    for (int i = 0; i < 2; ++i) {
      int c = threadIdx.x + i*256;       // 0..511
      int row = c >> 3, ch = c & 7;
      int sw = ch ^ (row & 7);
      const float* src = es + (size_t)(e0+row)*64 + ch*8;
      float4 f0 = *(const float4*)src;
      float4 f1 = *(const float4*)(src + 4);
      unsigned short tmp[8];
      tmp[0]=f2b(f0.x); tmp[1]=f2b(f0.y); tmp[2]=f2b(f0.z); tmp[3]=f2b(f0.w);
      tmp[4]=f2b(f1.x); tmp[5]=f2b(f1.y); tmp[6]=f2b(f1.z); tmp[7]=f2b(f1.w);
      *(uint4*)&sA[row*64 + sw*8] = *(const uint4*)tmp;
    }
    __syncthreads();
    f32x4 acc[8];
    #pragma unroll
    for (int ct = 0; ct < 8; ++ct) acc[ct] = (f32x4){0.f,0.f,0.f,0.f};
    int row = w*16 + ln;
    #pragma unroll
    for (int s = 0; s < 2; ++s) {
      int ch = (s*4 + g) ^ (row & 7);
      bf16x8 bfr = *(const bf16x8*)&sA[row*64 + ch*8];
      #pragma unroll
      for (int ct = 0; ct < 8; ++ct) {
        bf16x8 wf = *(const bf16x8*)(wcef + (((size_t)(ct*2+s))*64 + l)*8);
        acc[ct] = __builtin_amdgcn_mfma_f32_16x16x32_bf16(wf, bfr, acc[ct], 0, 0, 0);
      }
    }
    // stage fp8 (+bias) into swizzled LDS
    #pragma unroll
    for (int ct = 0; ct < 8; ++ct) {
      int c0 = ct*16 + g*4;
      float4 bi = *(const float4*)(bce + c0);
      int pk = 0;
      pk = __builtin_amdgcn_cvt_pk_fp8_f32(acc[ct][0]+bi.x, acc[ct][1]+bi.y, pk, false);
      pk = __builtin_amdgcn_cvt_pk_fp8_f32(acc[ct][2]+bi.z, acc[ct][3]+bi.w, pk, true);
      int ch = ct ^ (row & 7);
      *(int*)&sO8[row*160 + ch*16 + g*4] = pk;
    }
    __syncthreads();
    // readback: 8 lanes x 16B = one full 128B fp8 row per 8-lane group
    int rrow = threadIdx.x >> 3;   // 0..31
    int rch  = threadIdx.x & 7;
    #pragma unroll
    for (int it = 0; it < 2; ++it) {
      int r = it*32 + rrow;
      int swc = rch ^ (r & 7);
      uint4 val = *(const uint4*)&sO8[r*160 + swc*16];
      int prow = pos[e0 + r];
      *(uint4*)(eb + (size_t)prow*128 + rch*16) = val;
    }
  }
}

// -------- CSR build --------
__global__ void __launch_bounds__(256) k_hist(const int* __restrict__ ei, int* __restrict__ cnt) {
  int t = blockIdx.x * 256 + threadIdx.x;
  if (t < NE) atomicAdd(&cnt[ei[NE + t]], 1);
}

__global__ void __launch_bounds__(256) k_scanA(const int* __restrict__ cnt,
    int* __restrict__ off, int* __restrict__ bsum) {
  __shared__ int s[256];
  int i = blockIdx.x * 256 + threadIdx.x;
  int v = (i < NN) ? cnt[i] : 0;
  s[threadIdx.x] = v;
  __syncthreads();
  #pragma unroll
  for (int d = 1; d < 256; d <<= 1) {
    int t = (threadIdx.x >= d) ? s[threadIdx.x - d] : 0;
    __syncthreads();
    s[threadIdx.x] += t;
    __syncthreads();
  }
  if (i < NN) off[i] = s[threadIdx.x] - v;
  if (threadIdx.x == 255) bsum[blockIdx.x] = s[255];
}

__global__ void __launch_bounds__(256) k_scanB(int* __restrict__ bsum, int nb) {
  __shared__ int s[256];
  int v = (threadIdx.x < nb) ? bsum[threadIdx.x] : 0;
  s[threadIdx.x] = v;
  __syncthreads();
  #pragma unroll
  for (int d = 1; d < 256; d <<= 1) {
    int t = (threadIdx.x >= d) ? s[threadIdx.x - d] : 0;
    __syncthreads();
    s[threadIdx.x] += t;
    __syncthreads();
  }
  if (threadIdx.x < nb) bsum[threadIdx.x] = s[threadIdx.x] - v;
}

__global__ void __launch_bounds__(256) k_scanC(int* __restrict__ off,
    const int* __restrict__ bsum, int* __restrict__ cur) {
  int i = blockIdx.x * 256 + threadIdx.x;
  if (i < NN) {
    int o = off[i] + bsum[blockIdx.x];
    off[i] = o;
    cur[i] = o;
  }
}

// records each edge's CSR slot (pos) and the slot's source node (srcs)
__global__ void __launch_bounds__(256) k_scatter(const int* __restrict__ ei,
    int* __restrict__ cur, int* __restrict__ pos, int* __restrict__ srcs) {
  int t = blockIdx.x * 256 + threadIdx.x;
  if (t < NE) {
    int d = ei[NE + t];
    int p = atomicAdd(&cur[d], 1);
    pos[t] = p;
    srcs[p] = ei[t];
  }
}

// -------- fused attention gather + beta-gate + LN + residual ReLU --------
// one wave per node; lane l owns channels 2l, 2l+1; head = l>>3
// eb rows CSR-sorted fp8; k/v fp8 gathers
__global__ void __launch_bounds__(256) k_attn(
    const int* __restrict__ off, const int* __restrict__ cnt,
    const int* __restrict__ srcs,
    const unsigned short* __restrict__ qb, const unsigned char* __restrict__ kb,
    const unsigned char* __restrict__ vb, const unsigned char* __restrict__ eb,
    const float* __restrict__ xr, const float* __restrict__ x,
    const float* __restrict__ Wb, const float* __restrict__ ln_g,
    const float* __restrict__ ln_b, float* __restrict__ out) {
  int wid = threadIdx.x >> 6, lane = threadIdx.x & 63;
  int n = blockIdx.x * 4 + wid;
  if (n >= NN) return;
  int c = lane * 2;

  unsigned int qu = *(const unsigned int*)(qb + (size_t)n*128 + c);
  float q0 = b2f((unsigned short)(qu & 0xffffu)), q1 = b2f((unsigned short)(qu >> 16));

  int start = off[n], m = cnt[n];
  const int* sp = srcs + start;
  const unsigned char* ep = eb + (size_t)start*128 + c;
  float acc0 = 0.f, acc1 = 0.f, den = 0.f;

  auto body = [&](unsigned int ku2, unsigned int eu2, unsigned int vu2) {
    f32x2 ef = __builtin_amdgcn_cvt_pk_f32_fp8((int)eu2, false);
    f32x2 kf = __builtin_amdgcn_cvt_pk_f32_fp8((int)ku2, false);
    f32x2 vf = __builtin_amdgcn_cvt_pk_f32_fp8((int)vu2, false);
    float p = q0*(kf[0] + ef[0]) + q1*(kf[1] + ef[1]);
    p += __shfl_xor(p, 1);
    p += __shfl_xor(p, 2);
    p += __shfl_xor(p, 4);
    float a = __expf(p * 0.25f);
    den  += a;
    acc0 += a * (vf[0] + ef[0]);
    acc1 += a * (vf[1] + ef[1]);
  };

  int i = 0;
  for (; i + 4 <= m; i += 4) {
    int sA = sp[i], sB = sp[i+1], sC = sp[i+2], sD = sp[i+3];
    unsigned int euA = *(const unsigned short*)(ep + (size_t)(i+0)*128);
    unsigned int euB = *(const unsigned short*)(ep + (size_t)(i+1)*128);
    unsigned int euC = *(const unsigned short*)(ep + (size_t)(i+2)*128);
    unsigned int euD = *(const unsigned short*)(ep + (size_t)(i+3)*128);
    unsigned int kuA = *(const unsigned short*)(kb + (size_t)sA*128 + c);
    unsigned int vuA = *(const unsigned short*)(vb + (size_t)sA*128 + c);
    unsigned int kuB = *(const unsigned short*)(kb + (size_t)sB*128 + c);
    unsigned int vuB = *(const unsigned short*)(vb + (size_t)sB*128 + c);
    unsigned int kuC = *(const unsigned short*)(kb + (size_t)sC*128 + c);
    unsigned int vuC = *(const unsigned short*)(vb + (size_t)sC*128 + c);
    unsigned int kuD = *(const unsigned short*)(kb + (size_t)sD*128 + c);
    unsigned int vuD = *(const unsigned short*)(vb + (size_t)sD*128 + c);
    body(kuA, euA, vuA);
    body(kuB, euB, vuB);
    body(kuC, euC, vuC);
    body(kuD, euD, vuD);
  }
  for (; i < m; ++i) {
    int sA = sp[i];
    unsigned int euA = *(const unsigned short*)(ep + (size_t)i*128);
    unsigned int kuA = *(const unsigned short*)(kb + (size_t)sA*128 + c);
    unsigned int vuA = *(const unsigned short*)(vb + (size_t)sA*128 + c);
    body(kuA, euA, vuA);
  }

  float inv = (m > 0) ? 1.f / den : 0.f;
  float o0 = acc0 * inv, o1 = acc1 * inv;

  // epilogue
  float2 r = *(const float2*)(xr + (size_t)n*128 + c);
  float p = o0*Wb[c] + o1*Wb[c+1] + r.x*Wb[128+c] + r.y*Wb[128+c+1]
          + (o0-r.x)*Wb[256+c] + (o1-r.y)*Wb[256+c+1];
  #pragma unroll
  for (int offs = 32; offs > 0; offs >>= 1) p += __shfl_xor(p, offs);
  float beta = 1.f / (1.f + __expf(-p));
  float g0 = beta*r.x + (1.f-beta)*o0;
  float g1 = beta*r.y + (1.f-beta)*o1;
  float msum = g0 + g1;
  #pragma unroll
  for (int offs = 32; offs > 0; offs >>= 1) msum += __shfl_xor(msum, offs);
  msum *= (1.f/128.f);
  float d0 = g0 - msum, d1 = g1 - msum;
  float vv = d0*d0 + d1*d1;
  #pragma unroll
  for (int offs = 32; offs > 0; offs >>= 1) vv += __shfl_xor(vv, offs);
  vv *= (1.f/128.f);
  float rs = rsqrtf(vv + 1e-5f);
  float n0 = d0*rs*ln_g[c]   + ln_b[c];
  float n1 = d1*rs*ln_g[c+1] + ln_b[c+1];
  float2 xv = *(const float2*)(x + (size_t)n*128 + c);
  float2 res;
  res.x = xv.x + fmaxf(n0, 0.f);
  res.y = xv.y + fmaxf(n1, 0.f);
  *(float2*)(out + (size_t)n*128 + c) = res;
}

extern "C" void kernel_launch(void* const* d_in, const int* in_sizes, int n_in,
                              void* d_out, int out_size, void* d_ws, size_t ws_size,
                              hipStream_t stream) {
  const float* node   = (const float*)d_in[0];
  const int*   ei     = (const int*)  d_in[1];
  const float* es     = (const float*)d_in[2];
  const float* W_edge = (const float*)d_in[3];
  const float* b_edge = (const float*)d_in[4];
  const float* Wq     = (const float*)d_in[5];
  const float* bq     = (const float*)d_in[6];
  const float* Wk     = (const float*)d_in[7];
  const float* bk     = (const float*)d_in[8];
  const float* Wv     = (const float*)d_in[9];
  const float* bv     = (const float*)d_in[10];
  const float* We     = (const float*)d_in[11];
  const float* Wskip  = (const float*)d_in[12];
  const float* bskip  = (const float*)d_in[13];
  const float* Wbeta  = (const float*)d_in[14];
  const float* ln_g   = (const float*)d_in[15];
  const float* ln_b   = (const float*)d_in[16];

  char* ws = (char*)d_ws;
  unsigned short* wce   = (unsigned short*)(ws + WS_WCE);
  float*          bce   = (float*)(ws + WS_BCE);
  unsigned short* wcef  = (unsigned short*)(ws + WS_WCEF);
  unsigned short* wallf = (unsigned short*)(ws + WS_WALLF);
  float*          ball  = (float*)(ws + WS_BALL);
  unsigned short* qb  = (unsigned short*)(ws + WS_QB);
  unsigned char*  kb  = (unsigned char*)(ws + WS_KB);
  unsigned char*  vb  = (unsigned char*)(ws + WS_VB);
  float*          xr  = (float*)(ws + WS_XR);
  unsigned char*  eb  = (unsigned char*)(ws + WS_EB);
  int*            cnt = (int*)(ws + WS_CNT);
  int*            off = (int*)(ws + WS_OFF);
  int*            cur = (int*)(ws + WS_CUR);
  int*            bsm = (int*)(ws + WS_BSUM);
  int*            pos = (int*)(ws + WS_POS);
  int*            srcs= (int*)(ws + WS_SRCS);

  hipMemsetAsync(cnt, 0, (size_t)NN*4, stream);

  k_prep<<<64, 128, 0, stream>>>(W_edge, b_edge, We, wce, bce);
  k_pack_wce<<<16, 64, 0, stream>>>(wce, wcef);
  k_pack_wall<<<128, 64, 0, stream>>>(Wq, Wk, Wv, Wskip, wallf);
  k_pack_bias<<<4, 128, 0, stream>>>(bq, bk, bv, bskip, ball);

  const int nbScan = (NN + 255)/256;  // 196
  k_hist<<<(NE + 255)/256, 256, 0, stream>>>(ei, cnt);
  k_scanA<<<nbScan, 256, 0, stream>>>(cnt, off, bsm);
  k_scanB<<<1, 256, 0, stream>>>(bsm, nbScan);
  k_scanC<<<nbScan, 256, 0, stream>>>(off, bsm, cur);
  k_scatter<<<(NE + 255)/256, 256, 0, stream>>>(ei, cur, pos, srcs);

  // fused node+edge MFMA: node tiles = ceil(NN/64)*4 = 3128 (b%5==0),
  // edge tiles = NE/64 = 12500 (other b). grid sized so both ranges covered.
  const int nodeTiles = ((NN + 63)/64) * 4;   // 3128
  const int grid = 5 * nodeTiles;             // 15640 -> edge capacity 12512 >= 12500
  k_mfma_all<<<grid, 256, 0, stream>>>(node, wallf, ball, qb, kb, vb, xr,
                                       es, wcef, bce, pos, eb);

  k_attn<<<(NN + 3)/4, 256, 0, stream>>>(off, cnt, srcs, qb, kb, vb, eb,
                                         xr, node, Wbeta, ln_g, ln_b, (float*)d_out);
}